// Round 1
// baseline (391.876 us; speedup 1.0000x reference)
//
#include <hip/hip_runtime.h>
#include <stdint.h>

// out[bm,q,h] = sum_k s[bm,q,k] * v[bm,k,h]
// bm=64, QT=KVT=1024, H=64, fp32 in/out. Memory-bound (302 MB @ ~6.3 TB/s ~ 48us floor).
// Strategy: cast to bf16 on the fly (2% absmax threshold permits), MFMA 16x16x32,
// register-prefetch double-buffering of the global stream.

typedef __bf16 bf16x8 __attribute__((ext_vector_type(8)));
typedef float  f32x4  __attribute__((ext_vector_type(4)));

#define QTDIM 1024
#define KVDIM 1024
#define HDIM  64
#define QTILE 128
#define BK    64
#define NK    (KVDIM / BK)   // 16
#define SSTR  72             // LDS row stride in bf16 elems; 144 B rows -> 16B aligned
#define THREADS 256

// truncate two f32 to bf16 and pack (hi<<16)|lo in one v_perm_b32
__device__ __forceinline__ uint32_t pack_bf16_2(float lo, float hi) {
    union { float f; uint32_t u; } a, b;
    a.f = lo; b.f = hi;
    return __builtin_amdgcn_perm(b.u, a.u, 0x07060302u);
}

__global__ __launch_bounds__(THREADS, 2) void svbmm_kernel(
    const float* __restrict__ s, const float* __restrict__ v, float* __restrict__ out)
{
    __shared__ uint16_t s_sm[QTILE * SSTR];  // 18432 B, bf16 s-tile [128][72]
    __shared__ uint16_t vt_sm[HDIM * SSTR];  //  9216 B, bf16 v^T tile [h][k] [64][72]

    const int tid = threadIdx.x;
    const int bm  = blockIdx.y;
    const int q0  = blockIdx.x * QTILE;

    const float* sp = s   + ((size_t)bm * QTDIM + q0) * (size_t)KVDIM;
    const float* vp = v   + (size_t)bm * KVDIM * HDIM;
    float*       op = out + ((size_t)bm * QTDIM + q0) * (size_t)HDIM;

    // staging assignment
    const int srow = tid >> 4;          // 0..15 (row base; +16*i)
    const int scol = (tid & 15) << 2;   // 0..60 (float4 col within BK)
    const int vh   = tid & 63;          // h lane (contiguous in global v)
    const int vk0  = (tid >> 6) << 4;   // 0,16,32,48 (k base; 16 k's per thread)

    float4 sreg[8];
    float  vreg[16];

    // prologue: issue loads for kt = 0
    {
        const float* sb = sp + srow * KVDIM + scol;
        #pragma unroll
        for (int i = 0; i < 8; ++i)
            sreg[i] = *(const float4*)(sb + i * 16 * KVDIM);
        const float* vb = vp + vk0 * HDIM + vh;
        #pragma unroll
        for (int j = 0; j < 16; ++j)
            vreg[j] = vb[j * HDIM];
    }

    f32x4 acc[2][4];
    #pragma unroll
    for (int mt = 0; mt < 2; ++mt)
        #pragma unroll
        for (int nt = 0; nt < 4; ++nt)
            acc[mt][nt] = (f32x4){0.f, 0.f, 0.f, 0.f};

    const int wave = tid >> 6;
    const int lane = tid & 63;
    const int lrow = lane & 15;
    const int quad = lane >> 4;

    #pragma unroll 1
    for (int kt = 0; kt < NK; ++kt) {
        // ---- cvt + store current tile to LDS (implicit vmcnt wait on sreg/vreg) ----
        #pragma unroll
        for (int i = 0; i < 8; ++i) {
            float4 f = sreg[i];
            uint32_t u01 = pack_bf16_2(f.x, f.y);
            uint32_t u23 = pack_bf16_2(f.z, f.w);
            uint32_t* dst = (uint32_t*)&s_sm[(srow + i * 16) * SSTR + scol];
            dst[0] = u01;
            dst[1] = u23;
        }
        #pragma unroll
        for (int p = 0; p < 8; ++p) {
            uint32_t u = pack_bf16_2(vreg[2 * p], vreg[2 * p + 1]);
            *(uint32_t*)&vt_sm[vh * SSTR + vk0 + 2 * p] = u;
        }
        __syncthreads();

        // ---- issue next tile's global loads (in flight during compute) ----
        if (kt + 1 < NK) {
            const float* sb = sp + srow * KVDIM + (kt + 1) * BK + scol;
            #pragma unroll
            for (int i = 0; i < 8; ++i)
                sreg[i] = *(const float4*)(sb + i * 16 * KVDIM);
            const float* vb = vp + ((kt + 1) * BK + vk0) * HDIM + vh;
            #pragma unroll
            for (int j = 0; j < 16; ++j)
                vreg[j] = vb[j * HDIM];
        }

        // ---- MFMA on current LDS tile ----
        #pragma unroll
        for (int kk = 0; kk < 2; ++kk) {
            const int col = kk * 32 + quad * 8;
            bf16x8 a[2], b[4];
            #pragma unroll
            for (int mt = 0; mt < 2; ++mt)
                a[mt] = *(const bf16x8*)&s_sm[(wave * 32 + mt * 16 + lrow) * SSTR + col];
            #pragma unroll
            for (int nt = 0; nt < 4; ++nt)
                b[nt] = *(const bf16x8*)&vt_sm[(nt * 16 + lrow) * SSTR + col];
            #pragma unroll
            for (int mt = 0; mt < 2; ++mt)
                #pragma unroll
                for (int nt = 0; nt < 4; ++nt)
                    acc[mt][nt] = __builtin_amdgcn_mfma_f32_16x16x32_bf16(
                        a[mt], b[nt], acc[mt][nt], 0, 0, 0);
        }
        __syncthreads();
    }

    // ---- epilogue: D layout row = quad*4 + r, col = lane&15 (m89/m91-verified) ----
    #pragma unroll
    for (int mt = 0; mt < 2; ++mt) {
        #pragma unroll
        for (int nt = 0; nt < 4; ++nt) {
            #pragma unroll
            for (int r = 0; r < 4; ++r) {
                const int row = wave * 32 + mt * 16 + quad * 4 + r;
                const int col = nt * 16 + lrow;
                op[row * HDIM + col] = acc[mt][nt][r];
            }
        }
    }
}

extern "C" void kernel_launch(void* const* d_in, const int* in_sizes, int n_in,
                              void* d_out, int out_size, void* d_ws, size_t ws_size,
                              hipStream_t stream) {
    const float* s = (const float*)d_in[0];
    const float* v = (const float*)d_in[1];
    float* out = (float*)d_out;
    const int BM = in_sizes[0] / (QTDIM * KVDIM);  // 64
    dim3 grid(QTDIM / QTILE, BM);
    svbmm_kernel<<<grid, THREADS, 0, stream>>>(s, v, out);
}

// Round 2
// 381.642 us; speedup vs baseline: 1.0268x; 1.0268x over previous
//
#include <hip/hip_runtime.h>
#include <stdint.h>

// out[bm,q,h] = sum_k s[bm,q,k] * v[bm,k,h]
// bm=64, QT=KVT=1024, H=64, fp32 in/out. Memory-bound: 302 MB HBM @ ~6.3 TB/s => ~48us floor.
// bf16 MFMA (2% tolerance permits). Single-barrier double-buffered K-loop so the
// global prefetch survives the barrier's implicit vmcnt(0) drain.

typedef __bf16 bf16x8 __attribute__((ext_vector_type(8)));
typedef float  f32x4  __attribute__((ext_vector_type(4)));

#define QTDIM 1024
#define KVDIM 1024
#define HDIM  64
#define QTILE 64
#define BK    64
#define NK    (KVDIM / BK)   // 16
#define SSTR  72             // LDS row stride (bf16 elems); 144 B rows, 16B-aligned
#define THREADS 256

// truncate two f32 to bf16, pack (hi<<16)|lo in one v_perm_b32
__device__ __forceinline__ uint32_t pack_bf16_2(float lo, float hi) {
    union { float f; uint32_t u; } a, b;
    a.f = lo; b.f = hi;
    return __builtin_amdgcn_perm(b.u, a.u, 0x07060302u);
}

__global__ __launch_bounds__(THREADS, 4) void svbmm_kernel(
    const float* __restrict__ s, const float* __restrict__ v, float* __restrict__ out)
{
    // double-buffered bf16 tiles: s-tile [64][72], v^T-tile [h][k] [64][72]
    __shared__ uint16_t s_sm[2][QTILE * SSTR];   // 2 x 9216 B
    __shared__ uint16_t vt_sm[2][HDIM * SSTR];   // 2 x 9216 B  (total 36864 B)

    const int tid = threadIdx.x;
    const int bm  = blockIdx.y;
    const int q0  = blockIdx.x * QTILE;

    const float* sp = s   + ((size_t)bm * QTDIM + q0) * (size_t)KVDIM;
    const float* vp = v   + (size_t)bm * KVDIM * HDIM;
    float*       op = out + ((size_t)bm * QTDIM + q0) * (size_t)HDIM;

    // staging assignment
    const int srow = tid >> 4;          // 0..15 (+16*i, i<4 covers 64 rows)
    const int scol = (tid & 15) << 2;   // float4 col within BK
    const int vh   = tid & 63;          // h lane (contiguous in global v)
    const int vk0  = (tid >> 6) << 4;   // 0,16,32,48 (16 k's per thread)

    float4 sreg[4];
    float  vreg[16];

    // prologue: loads for kt = 0
    {
        const float* sb = sp + srow * KVDIM + scol;
        #pragma unroll
        for (int i = 0; i < 4; ++i)
            sreg[i] = *(const float4*)(sb + i * 16 * KVDIM);
        const float* vb = vp + vk0 * HDIM + vh;
        #pragma unroll
        for (int j = 0; j < 16; ++j)
            vreg[j] = vb[j * HDIM];
    }

    f32x4 acc[4];
    #pragma unroll
    for (int nt = 0; nt < 4; ++nt)
        acc[nt] = (f32x4){0.f, 0.f, 0.f, 0.f};

    const int wave = tid >> 6;   // wave owns q-rows [wave*16, wave*16+16)
    const int lane = tid & 63;
    const int lrow = lane & 15;
    const int quad = lane >> 4;

    #pragma unroll 2
    for (int kt = 0; kt < NK; ++kt) {
        const int buf = kt & 1;

        // ---- cvt + store tile kt to LDS (vmcnt waits are pipelined per-use) ----
        #pragma unroll
        for (int i = 0; i < 4; ++i) {
            float4 f = sreg[i];
            uint64_t u = (uint64_t)pack_bf16_2(f.x, f.y)
                       | ((uint64_t)pack_bf16_2(f.z, f.w) << 32);
            *(uint64_t*)&s_sm[buf][(srow + i * 16) * SSTR + scol] = u;
        }
        #pragma unroll
        for (int p = 0; p < 4; ++p) {
            uint64_t u = (uint64_t)pack_bf16_2(vreg[4 * p],     vreg[4 * p + 1])
                       | ((uint64_t)pack_bf16_2(vreg[4 * p + 2], vreg[4 * p + 3]) << 32);
            *(uint64_t*)&vt_sm[buf][vh * SSTR + vk0 + 4 * p] = u;
        }

        // single barrier: publishes buf, and guarantees buf^1's readers from
        // iter kt-1 are done before iter kt+1 overwrites it. Zero outstanding
        // VMEM here => the implicit vmcnt(0) is free.
        __syncthreads();

        // ---- issue tile kt+1 loads AFTER the barrier: they stay in flight
        //      across the back-edge until next iteration's cvt phase ----
        if (kt + 1 < NK) {
            const float* sb = sp + srow * KVDIM + (kt + 1) * BK + scol;
            #pragma unroll
            for (int i = 0; i < 4; ++i)
                sreg[i] = *(const float4*)(sb + i * 16 * KVDIM);
            const float* vb = vp + ((kt + 1) * BK + vk0) * HDIM + vh;
            #pragma unroll
            for (int j = 0; j < 16; ++j)
                vreg[j] = vb[j * HDIM];
        }

        // ---- MFMA on tile kt ----
        #pragma unroll
        for (int kk = 0; kk < 2; ++kk) {
            const int col = kk * 32 + quad * 8;
            bf16x8 a = *(const bf16x8*)&s_sm[buf][(wave * 16 + lrow) * SSTR + col];
            #pragma unroll
            for (int nt = 0; nt < 4; ++nt) {
                bf16x8 b = *(const bf16x8*)&vt_sm[buf][(nt * 16 + lrow) * SSTR + col];
                acc[nt] = __builtin_amdgcn_mfma_f32_16x16x32_bf16(a, b, acc[nt], 0, 0, 0);
            }
        }
        // no second barrier: next iteration writes buf^1, already safe.
    }

    // ---- epilogue: D layout row = quad*4 + r, col = lane&15 (m89/m91-verified) ----
    #pragma unroll
    for (int nt = 0; nt < 4; ++nt) {
        #pragma unroll
        for (int r = 0; r < 4; ++r) {
            const int row = wave * 16 + quad * 4 + r;
            const int col = nt * 16 + lrow;
            op[row * HDIM + col] = acc[nt][r];
        }
    }
}

extern "C" void kernel_launch(void* const* d_in, const int* in_sizes, int n_in,
                              void* d_out, int out_size, void* d_ws, size_t ws_size,
                              hipStream_t stream) {
    const float* s = (const float*)d_in[0];
    const float* v = (const float*)d_in[1];
    float* out = (float*)d_out;
    const int BM = in_sizes[0] / (QTDIM * KVDIM);  // 64
    dim3 grid(QTDIM / QTILE, BM);                  // 16 x 64 = 1024 blocks = 4/CU
    svbmm_kernel<<<grid, THREADS, 0, stream>>>(s, v, out);
}